// Round 4
// baseline (124.606 us; speedup 1.0000x reference)
//
#include <hip/hip_runtime.h>
#include <math.h>

namespace {

constexpr int Bn = 64;   // batch
constexpr int Cn = 128;  // channels
constexpr int Tn = 512;  // time
constexpr int Hn = 256;  // hidden
constexpr int MR = 128;  // t-rows per block
constexpr int TB = Tn / MR;  // 4 tiles/batch -> grid 256 (1 block/CU)
constexpr int K1 = Cn * 9;   // 1152
constexpr int K2 = Hn * 9;   // 2304
constexpr int FC = 16;       // feats per k-chunk
constexpr int KC = 144;      // k per chunk = 9 j-slots * 16 feats
constexpr int KSS = 152;     // act row stride shorts (304B: pos cycles x3 mod 8 -> conflict-free)
constexpr int HS = 272;      // h1 row stride shorts (544B: row-groups at banks 0/8/16/24)
constexpr int NCH1 = 8;      // 8 * 144 = 1152
constexpr int NCH2 = 16;     // 16 * 144 = 2304
constexpr float LN_EPS = 1e-5f;

typedef __attribute__((ext_vector_type(8))) short short8;
typedef __attribute__((ext_vector_type(16))) float f32x16;

// fp32 -> bf16 bits, round-to-nearest-even
__device__ __forceinline__ unsigned short f2bf(float f) {
  unsigned int u = __builtin_bit_cast(unsigned int, f);
  u = (u + 0x7fffu + ((u >> 16) & 1u)) >> 16;
  return (unsigned short)u;
}
__device__ __forceinline__ float bf2f(unsigned short u) {
  unsigned int v = (unsigned int)u << 16;
  return __builtin_bit_cast(float, v);
}

// Closed-form uniform cubic B-spline on grid g[j] = 0.4*(j-3) - 1.
// Cell i = floor(2.5*z + 5.5); nonzero bases j = i-3..i. Slots pre-zeroed.
// Layout stride 16: basis j at rowp[j*16 + feat], silu at rowp[128 + feat].
__device__ __forceinline__ void emit_act(float z,
                                         unsigned short* __restrict__ rowp,
                                         int feat) {
  const float e = __expf(-z);
  const float sil = z * __builtin_amdgcn_rcpf(1.0f + e);
  rowp[128 + feat] = f2bf(sil);  // k-slot 8 = silu (pairs with base_w)
  const float p = z * 2.5f + 5.5f;
  const float fi = floorf(p);
  const int i = (int)fi;
  if (i >= 0 && i <= 10) {
    const float u = p - fi;
    const float u2 = u * u, u3 = u2 * u, t = 1.0f - u;
    const float w0 = t * t * t * (1.0f / 6.0f);
    const float w1 = (3.0f * u3 - 6.0f * u2 + 4.0f) * (1.0f / 6.0f);
    const float w2 =
        (-3.0f * u3 + 3.0f * u2 + 3.0f * u + 1.0f) * (1.0f / 6.0f);
    const float w3 = u3 * (1.0f / 6.0f);
    if (i >= 3) rowp[(i - 3) * 16 + feat] = f2bf(w0);
    if (i >= 2 && i <= 9) rowp[(i - 2) * 16 + feat] = f2bf(w1);
    if (i >= 1 && i <= 8) rowp[(i - 1) * 16 + feat] = f2bf(w2);
    if (i <= 7) rowp[i * 16 + feat] = f2bf(w3);
  }
}

}  // namespace

// ---------------------------------------------------------------------------
// Prep: blocks 0..255 pack weights bf16 with chunked extended-K layout
//   k = (feat>>4)*144 + j*16 + (feat&15), j=0..7 spline, j=8 base(silu);
// blocks 256..511: deterministic per-batch partial sums for LN stats.
// ---------------------------------------------------------------------------
__global__ __launch_bounds__(256) void kan_prep(
    const float* __restrict__ U, const float* __restrict__ bw1,
    const float* __restrict__ sw1, const float* __restrict__ ss1,
    const float* __restrict__ bw2, const float* __restrict__ sw2,
    const float* __restrict__ ss2, unsigned short* __restrict__ W1p,
    unsigned short* __restrict__ W2p, float* __restrict__ stats) {
  __shared__ float red[2][4];
  const int blk = blockIdx.x;
  if (blk < 256) {
    int idx = blk * 256 + threadIdx.x;  // 0..65535
    if (idx < Hn * Cn) {
      const int h = idx >> 7, c = idx & 127;
      const float* spw = sw1 + ((size_t)h * Cn + c) * 8;
      const float sc = ss1[h * Cn + c];
      unsigned short* dst = W1p + (size_t)h * K1 + (c >> 4) * KC + (c & 15);
#pragma unroll
      for (int j = 0; j < 8; ++j) dst[j * 16] = f2bf(spw[j] * sc);
      dst[8 * 16] = f2bf(bw1[h * Cn + c]);
    } else {
      idx -= Hn * Cn;
      const int c = idx >> 8, h = idx & 255;
      const float* spw = sw2 + ((size_t)c * Hn + h) * 8;
      const float sc = ss2[c * Hn + h];
      unsigned short* dst = W2p + (size_t)c * K2 + (h >> 4) * KC + (h & 15);
#pragma unroll
      for (int j = 0; j < 8; ++j) dst[j * 16] = f2bf(spw[j] * sc);
      dst[8 * 16] = f2bf(bw2[c * Hn + h]);
    }
  } else {
    const int sblk = blk - 256;
    const int b = sblk >> 2, q = sblk & 3;
    const float4* p =
        (const float4*)(U + (size_t)b * (Cn * Tn) + q * (Cn * Tn / 4));
    float s = 0.f, s2 = 0.f;
#pragma unroll 4
    for (int i = threadIdx.x; i < (Cn * Tn / 4) / 4; i += 256) {
      const float4 v = p[i];
      s += v.x + v.y + v.z + v.w;
      s2 += v.x * v.x + v.y * v.y + v.z * v.z + v.w * v.w;
    }
#pragma unroll
    for (int off = 32; off > 0; off >>= 1) {
      s += __shfl_down(s, off);
      s2 += __shfl_down(s2, off);
    }
    if ((threadIdx.x & 63) == 0) {
      red[0][threadIdx.x >> 6] = s;
      red[1][threadIdx.x >> 6] = s2;
    }
    __syncthreads();
    if (threadIdx.x == 0) {
      stats[b * 8 + q * 2 + 0] = red[0][0] + red[0][1] + red[0][2] + red[0][3];
      stats[b * 8 + q * 2 + 1] = red[1][0] + red[1][1] + red[1][2] + red[1][3];
    }
  }
}

// ---------------------------------------------------------------------------
// Fused LN -> KAN1 -> KAN2 -> residual. 256 blocks x 1024 threads (16 waves).
// Layer1: wave tile (m=64,n=32), mfma 32x32x16, acc 2x16. Layer2: (32,32).
// Double-buffered 16-feat act chunks; 9-deep B-prefetch regs reloaded
// right after last use -> load-use distance ~ one full chunk.
// ---------------------------------------------------------------------------
__global__ __launch_bounds__(1024, 4) void kan_fused(
    const float* __restrict__ U, const float* __restrict__ ln_w,
    const float* __restrict__ ln_b, const unsigned short* __restrict__ W1p,
    const unsigned short* __restrict__ W2p, const float* __restrict__ stats,
    float* __restrict__ out) {
  __shared__ unsigned short s_buf[2][MR * KSS];  // 2 x 38912 B
  __shared__ unsigned short s_h1[MR * HS];       // 69632 B (bf16 h1)

  const int tid = threadIdx.x;
  const int b = blockIdx.x >> 2;
  const int t0 = (blockIdx.x & 3) * MR;

  const float* sp = stats + b * 8;
  const float ssum = sp[0] + sp[2] + sp[4] + sp[6];
  const float ssq = sp[1] + sp[3] + sp[5] + sp[7];
  const float inv_n = 1.0f / (float)(Cn * Tn);
  const float mean = ssum * inv_n;
  const float rstd = rsqrtf(ssq * inv_n - mean * mean + LN_EPS);

  const int w = tid >> 6;    // wave 0..15
  const int l = tid & 63;    // lane
  const int ln31 = l & 31;
  const int hl = l >> 5;     // k-half
  const int feat = tid & 15; // act feat within chunk
  const int rowq = tid >> 4; // act rows rowq, rowq+64 (wave-local: w*4..w*4+3)

  const short8 zz = {0, 0, 0, 0, 0, 0, 0, 0};

  // Wave-local zeroing of the 8 rows this wave scatters into (144 shorts/row).
  auto zero_rows = [&](unsigned short* nbuf) {
#pragma unroll
    for (int it = 0; it < 3; ++it) {
      const int i = l + it * 64;
      if (it < 2 || l < 16) {  // i < 144
        const int r8 = i / 18;
        const int off = i - r8 * 18;
        const int row = w * 4 + (r8 & 3) + (r8 >> 2) * 64;
        *(short8*)&nbuf[row * KSS + off * 8] = zz;
      }
    }
  };
  auto act1 = [&](int chunk, unsigned short* nbuf) {
    zero_rows(nbuf);
    const int c = chunk * FC + feat;
#pragma unroll
    for (int pp = 0; pp < 2; ++pp) {
      const int row = rowq + pp * 64;
      const int t = t0 + row;
      const float uv = U[((size_t)b * Cn + c) * Tn + t];
      const float z = (uv - mean) * rstd * ln_w[t * Cn + c] + ln_b[t * Cn + c];
      emit_act(z, nbuf + row * KSS, feat);
    }
  };
  auto act2 = [&](int chunk, unsigned short* nbuf) {
    zero_rows(nbuf);
#pragma unroll
    for (int pp = 0; pp < 2; ++pp) {
      const int row = rowq + pp * 64;
      const float z = bf2f(s_h1[row * HS + chunk * FC + feat]);
      emit_act(z, nbuf + row * KSS, feat);
    }
  };

  // ==================== Layer 1: M=128, N=256, K=1152 ====================
  const int mg = w >> 3;  // m-group: rows mg*64 + 0..63
  const int ng = w & 7;   // n-group: cols ng*32 + 0..31
  const unsigned short* wb1 = W1p + (size_t)(ng * 32 + ln31) * K1 + hl * 8;

  short8 breg[9];
#pragma unroll
  for (int ks = 0; ks < 9; ++ks) breg[ks] = *(const short8*)(wb1 + ks * 16);
  act1(0, s_buf[0]);
  __syncthreads();

  f32x16 acc1[2] = {};
  const int arow = mg * 64 + ln31;
  for (int k = 0; k < NCH1; ++k) {
    const unsigned short* cur = s_buf[k & 1];
    if (k < NCH1 - 1) act1(k + 1, s_buf[(k + 1) & 1]);
    const unsigned short* a0p = cur + arow * KSS + hl * 8;
#pragma unroll
    for (int ks = 0; ks < 9; ++ks) {
      const short8 a0 = *(const short8*)(a0p + ks * 16);
      const short8 a1 = *(const short8*)(a0p + 32 * KSS + ks * 16);
      const short8 bc = breg[ks];
      if (k < NCH1 - 1)
        breg[ks] = *(const short8*)(wb1 + (k + 1) * KC + ks * 16);
      acc1[0] =
          __builtin_amdgcn_mfma_f32_32x32x16_bf16(a0, bc, acc1[0], 0, 0, 0);
      acc1[1] =
          __builtin_amdgcn_mfma_f32_32x32x16_bf16(a1, bc, acc1[1], 0, 0, 0);
    }
    __syncthreads();
  }

  // ---- prefetch layer-2 chunk 0 B (hides under h1 write + act2) ----
  const int mg2 = w >> 2;  // rows mg2*32 + 0..31
  const int ng2 = w & 3;   // cols ng2*32 + 0..31
  const unsigned short* wb2 = W2p + (size_t)(ng2 * 32 + ln31) * K2 + hl * 8;
#pragma unroll
  for (int ks = 0; ks < 9; ++ks) breg[ks] = *(const short8*)(wb2 + ks * 16);

  // ---- h1 -> LDS bf16: C-layout col=lane&31, row=(reg&3)+8*(reg>>2)+4*hl --
#pragma unroll
  for (int q = 0; q < 2; ++q)
#pragma unroll
    for (int reg = 0; reg < 16; ++reg) {
      const int row = mg * 64 + q * 32 + 4 * hl + (reg & 3) + 8 * (reg >> 2);
      s_h1[row * HS + ng * 32 + ln31] = f2bf(acc1[q][reg]);
    }
  __syncthreads();
  act2(0, s_buf[0]);
  __syncthreads();

  // ==================== Layer 2: M=128, N=128, K=2304 ====================
  f32x16 acc2 = {};
  const int arow2 = mg2 * 32 + ln31;
  for (int k = 0; k < NCH2; ++k) {
    const unsigned short* cur = s_buf[k & 1];
    if (k < NCH2 - 1) act2(k + 1, s_buf[(k + 1) & 1]);
    const unsigned short* ap = cur + arow2 * KSS + hl * 8;
#pragma unroll
    for (int ks = 0; ks < 9; ++ks) {
      const short8 a = *(const short8*)(ap + ks * 16);
      const short8 bc = breg[ks];
      if (k < NCH2 - 1)
        breg[ks] = *(const short8*)(wb2 + (k + 1) * KC + ks * 16);
      acc2 = __builtin_amdgcn_mfma_f32_32x32x16_bf16(a, bc, acc2, 0, 0, 0);
    }
    __syncthreads();
  }

  // ==================== Epilogue: residual + store ====================
  const int c = ng2 * 32 + ln31;
#pragma unroll
  for (int g = 0; g < 4; ++g) {
    const int tbase = t0 + mg2 * 32 + 4 * hl + 8 * g;
    const size_t base = ((size_t)b * Cn + c) * Tn + tbase;
    const float4 uin = *(const float4*)(U + base);
    float4 o;
    o.x = uin.x + acc2[g * 4 + 0];
    o.y = uin.y + acc2[g * 4 + 1];
    o.z = uin.z + acc2[g * 4 + 2];
    o.w = uin.w + acc2[g * 4 + 3];
    *(float4*)(out + base) = o;
  }
}

extern "C" void kernel_launch(void* const* d_in, const int* in_sizes, int n_in,
                              void* d_out, int out_size, void* d_ws,
                              size_t ws_size, hipStream_t stream) {
  const float* U = (const float*)d_in[0];
  const float* ln_w = (const float*)d_in[1];
  const float* ln_b = (const float*)d_in[2];
  const float* bw1 = (const float*)d_in[3];
  const float* sw1 = (const float*)d_in[4];
  const float* ss1 = (const float*)d_in[5];
  const float* bw2 = (const float*)d_in[6];
  const float* sw2 = (const float*)d_in[7];
  const float* ss2 = (const float*)d_in[8];
  float* out = (float*)d_out;

  float* stats = (float*)d_ws;  // 64*8 floats
  unsigned short* W1p = (unsigned short*)((char*)d_ws + 4096);
  unsigned short* W2p = W1p + (size_t)Hn * K1;

  kan_prep<<<512, 256, 0, stream>>>(U, bw1, sw1, ss1, bw2, sw2, ss2, W1p, W2p,
                                    stats);
  kan_fused<<<Bn * TB, 1024, 0, stream>>>(U, ln_w, ln_b, W1p, W2p, stats, out);
}

// Round 5
// 122.123 us; speedup vs baseline: 1.0203x; 1.0203x over previous
//
#include <hip/hip_runtime.h>
#include <math.h>

namespace {

constexpr int Bn = 64;   // batch
constexpr int Cn = 128;  // channels
constexpr int Tn = 512;  // time
constexpr int Hn = 256;  // hidden
constexpr int MR = 64;   // t-rows per block
constexpr int TB = Tn / MR;  // 8 tiles/batch -> grid 512 (2 blocks/CU)
constexpr int K1 = Cn * 9;   // 1152
constexpr int K2 = Hn * 9;   // 2304
constexpr int FC = 16;       // feats per k-chunk
constexpr int KC = 144;      // k per chunk = 9 j-slots * 16 feats
constexpr int KSS = 152;     // act row stride shorts (304B -> 16B-pos cycles x3 mod 8)
constexpr int HS = 272;      // h1 row stride shorts (544B)
constexpr int NCH1 = 8;      // 8 * 16 = 128 c
constexpr int NCH2 = 16;     // 16 * 16 = 256 h
constexpr float LN_EPS = 1e-5f;

typedef __attribute__((ext_vector_type(8))) short short8;
typedef __attribute__((ext_vector_type(16))) float f32x16;

// fp32 -> bf16 bits, round-to-nearest-even
__device__ __forceinline__ unsigned short f2bf(float f) {
  unsigned int u = __builtin_bit_cast(unsigned int, f);
  u = (u + 0x7fffu + ((u >> 16) & 1u)) >> 16;
  return (unsigned short)u;
}
__device__ __forceinline__ float bf2f(unsigned short u) {
  unsigned int v = (unsigned int)u << 16;
  return __builtin_bit_cast(float, v);
}

// Closed-form uniform cubic B-spline on grid g[j] = 0.4*(j-3) - 1.
// Cell i = floor(2.5*z + 5.5); nonzero bases j = i-3..i. Slots pre-zeroed.
// Layout stride 16: basis j at rowp[j*16 + feat], silu at rowp[128 + feat].
__device__ __forceinline__ void emit_act(float z,
                                         unsigned short* __restrict__ rowp,
                                         int feat) {
  const float e = __expf(-z);
  const float sil = z * __builtin_amdgcn_rcpf(1.0f + e);
  rowp[128 + feat] = f2bf(sil);  // k-slot 8 = silu (pairs with base_w)
  const float p = z * 2.5f + 5.5f;
  const float fi = floorf(p);
  const int i = (int)fi;
  if (i >= 0 && i <= 10) {
    const float u = p - fi;
    const float u2 = u * u, u3 = u2 * u, t = 1.0f - u;
    const float w0 = t * t * t * (1.0f / 6.0f);
    const float w1 = (3.0f * u3 - 6.0f * u2 + 4.0f) * (1.0f / 6.0f);
    const float w2 =
        (-3.0f * u3 + 3.0f * u2 + 3.0f * u + 1.0f) * (1.0f / 6.0f);
    const float w3 = u3 * (1.0f / 6.0f);
    if (i >= 3) rowp[(i - 3) * 16 + feat] = f2bf(w0);
    if (i >= 2 && i <= 9) rowp[(i - 2) * 16 + feat] = f2bf(w1);
    if (i >= 1 && i <= 8) rowp[(i - 1) * 16 + feat] = f2bf(w2);
    if (i <= 7) rowp[i * 16 + feat] = f2bf(w3);
  }
}

}  // namespace

// ---------------------------------------------------------------------------
// Prep: blocks 0..255 pack weights bf16 with chunked extended-K layout
//   k = (feat>>4)*144 + j*16 + (feat&15), j=0..7 spline, j=8 base(silu);
// blocks 256..511: deterministic per-batch partial sums for LN stats.
// ---------------------------------------------------------------------------
__global__ __launch_bounds__(256) void kan_prep(
    const float* __restrict__ U, const float* __restrict__ bw1,
    const float* __restrict__ sw1, const float* __restrict__ ss1,
    const float* __restrict__ bw2, const float* __restrict__ sw2,
    const float* __restrict__ ss2, unsigned short* __restrict__ W1p,
    unsigned short* __restrict__ W2p, float* __restrict__ stats) {
  __shared__ float red[2][4];
  const int blk = blockIdx.x;
  if (blk < 256) {
    int idx = blk * 256 + threadIdx.x;  // 0..65535
    if (idx < Hn * Cn) {
      const int h = idx >> 7, c = idx & 127;
      const float* spw = sw1 + ((size_t)h * Cn + c) * 8;
      const float sc = ss1[h * Cn + c];
      unsigned short* dst = W1p + (size_t)h * K1 + (c >> 4) * KC + (c & 15);
#pragma unroll
      for (int j = 0; j < 8; ++j) dst[j * 16] = f2bf(spw[j] * sc);
      dst[8 * 16] = f2bf(bw1[h * Cn + c]);
    } else {
      idx -= Hn * Cn;
      const int c = idx >> 8, h = idx & 255;
      const float* spw = sw2 + ((size_t)c * Hn + h) * 8;
      const float sc = ss2[c * Hn + h];
      unsigned short* dst = W2p + (size_t)c * K2 + (h >> 4) * KC + (h & 15);
#pragma unroll
      for (int j = 0; j < 8; ++j) dst[j * 16] = f2bf(spw[j] * sc);
      dst[8 * 16] = f2bf(bw2[c * Hn + h]);
    }
  } else {
    const int sblk = blk - 256;
    const int b = sblk >> 2, q = sblk & 3;
    const float4* p =
        (const float4*)(U + (size_t)b * (Cn * Tn) + q * (Cn * Tn / 4));
    float s = 0.f, s2 = 0.f;
#pragma unroll 4
    for (int i = threadIdx.x; i < (Cn * Tn / 4) / 4; i += 256) {
      const float4 v = p[i];
      s += v.x + v.y + v.z + v.w;
      s2 += v.x * v.x + v.y * v.y + v.z * v.z + v.w * v.w;
    }
#pragma unroll
    for (int off = 32; off > 0; off >>= 1) {
      s += __shfl_down(s, off);
      s2 += __shfl_down(s2, off);
    }
    if ((threadIdx.x & 63) == 0) {
      red[0][threadIdx.x >> 6] = s;
      red[1][threadIdx.x >> 6] = s2;
    }
    __syncthreads();
    if (threadIdx.x == 0) {
      stats[b * 8 + q * 2 + 0] = red[0][0] + red[0][1] + red[0][2] + red[0][3];
      stats[b * 8 + q * 2 + 1] = red[1][0] + red[1][1] + red[1][2] + red[1][3];
    }
  }
}

// ---------------------------------------------------------------------------
// Fused LN -> KAN1 -> KAN2 -> residual. 512 blocks x 512 threads (8 waves),
// 64 t-rows/block, 72 KB LDS -> 2 blocks/CU (two barrier domains overlap).
// Layer1: wave tile (m=64,n=32) via 2x mfma_32x32x16. Layer2: (32,32).
// 9-deep B-prefetch in regs (needs ~110 VGPR -> launch_bounds cap 128).
// ---------------------------------------------------------------------------
__global__ __launch_bounds__(512, 4) void kan_fused(
    const float* __restrict__ U, const float* __restrict__ ln_w,
    const float* __restrict__ ln_b, const unsigned short* __restrict__ W1p,
    const unsigned short* __restrict__ W2p, const float* __restrict__ stats,
    float* __restrict__ out) {
  __shared__ unsigned short s_buf[2][MR * KSS];  // 2 x 19456 B
  __shared__ unsigned short s_h1[MR * HS];       // 34816 B (bf16 h1)

  const int tid = threadIdx.x;
  const int b = blockIdx.x >> 3;
  const int t0 = (blockIdx.x & 7) * MR;

  const float* sp = stats + b * 8;
  const float ssum = sp[0] + sp[2] + sp[4] + sp[6];
  const float ssq = sp[1] + sp[3] + sp[5] + sp[7];
  const float inv_n = 1.0f / (float)(Cn * Tn);
  const float mean = ssum * inv_n;
  const float rstd = rsqrtf(ssq * inv_n - mean * mean + LN_EPS);

  const int w = tid >> 6;     // wave 0..7
  const int l = tid & 63;     // lane
  const int ln31 = l & 31;
  const int hl = l >> 5;      // k-half
  const int feat = tid & 15;  // act feat within chunk
  const int rowq = tid >> 4;  // act rows rowq, rowq+32 (wave-local w*4..w*4+3)

  const short8 zz = {0, 0, 0, 0, 0, 0, 0, 0};

  // Wave-local zeroing of the 8 rows this wave scatters into (144 shorts/row).
  auto zero_rows = [&](unsigned short* nbuf) {
#pragma unroll
    for (int it = 0; it < 3; ++it) {
      const int i = l + it * 64;
      if (it < 2 || l < 16) {  // i < 144
        const int r8 = i / 18;
        const int off = i - r8 * 18;
        const int row = w * 4 + (r8 & 3) + (r8 >> 2) * 32;
        *(short8*)&nbuf[row * KSS + off * 8] = zz;
      }
    }
  };
  auto act1 = [&](int chunk, unsigned short* nbuf) {
    zero_rows(nbuf);
    const int c = chunk * FC + feat;
#pragma unroll
    for (int pp = 0; pp < 2; ++pp) {
      const int row = rowq + pp * 32;
      const int t = t0 + row;
      const float uv = U[((size_t)b * Cn + c) * Tn + t];
      const float z = (uv - mean) * rstd * ln_w[t * Cn + c] + ln_b[t * Cn + c];
      emit_act(z, nbuf + row * KSS, feat);
    }
  };
  auto act2 = [&](int chunk, unsigned short* nbuf) {
    zero_rows(nbuf);
#pragma unroll
    for (int pp = 0; pp < 2; ++pp) {
      const int row = rowq + pp * 32;
      const float z = bf2f(s_h1[row * HS + chunk * FC + feat]);
      emit_act(z, nbuf + row * KSS, feat);
    }
  };

  // ==================== Layer 1: M=64, N=256, K=1152 ====================
  // wave w owns cols w*32..w*32+31, rows 0..63 (2 m-subtiles)
  const unsigned short* wb1 = W1p + (size_t)(w * 32 + ln31) * K1 + hl * 8;

  short8 breg[9];
#pragma unroll
  for (int ks = 0; ks < 9; ++ks) breg[ks] = *(const short8*)(wb1 + ks * 16);
  act1(0, s_buf[0]);
  __syncthreads();

  f32x16 acc1[2] = {};
  for (int k = 0; k < NCH1; ++k) {
    const unsigned short* cur = s_buf[k & 1];
    if (k < NCH1 - 1) act1(k + 1, s_buf[(k + 1) & 1]);
    const unsigned short* a0p = cur + ln31 * KSS + hl * 8;
#pragma unroll
    for (int ks = 0; ks < 9; ++ks) {
      const short8 a0 = *(const short8*)(a0p + ks * 16);
      const short8 a1 = *(const short8*)(a0p + 32 * KSS + ks * 16);
      const short8 bc = breg[ks];
      if (k < NCH1 - 1)
        breg[ks] = *(const short8*)(wb1 + (k + 1) * KC + ks * 16);
      acc1[0] =
          __builtin_amdgcn_mfma_f32_32x32x16_bf16(a0, bc, acc1[0], 0, 0, 0);
      acc1[1] =
          __builtin_amdgcn_mfma_f32_32x32x16_bf16(a1, bc, acc1[1], 0, 0, 0);
    }
    __syncthreads();
  }

  // ---- prefetch layer-2 chunk 0 B (hides under h1 write + act2) ----
  const int mg2 = w >> 2;  // rows mg2*32 + 0..31
  const int ng2 = w & 3;   // cols ng2*32 + 0..31
  const unsigned short* wb2 = W2p + (size_t)(ng2 * 32 + ln31) * K2 + hl * 8;
#pragma unroll
  for (int ks = 0; ks < 9; ++ks) breg[ks] = *(const short8*)(wb2 + ks * 16);

  // ---- h1 -> LDS bf16: C-layout col=lane&31, row=(reg&3)+8*(reg>>2)+4*hl --
#pragma unroll
  for (int q = 0; q < 2; ++q)
#pragma unroll
    for (int reg = 0; reg < 16; ++reg) {
      const int row = q * 32 + 4 * hl + (reg & 3) + 8 * (reg >> 2);
      s_h1[row * HS + w * 32 + ln31] = f2bf(acc1[q][reg]);
    }
  __syncthreads();
  act2(0, s_buf[0]);
  __syncthreads();

  // ==================== Layer 2: M=64, N=128, K=2304 ====================
  f32x16 acc2 = {};
  const int arow2 = mg2 * 32 + ln31;
  for (int k = 0; k < NCH2; ++k) {
    const unsigned short* cur = s_buf[k & 1];
    if (k < NCH2 - 1) act2(k + 1, s_buf[(k + 1) & 1]);
    const unsigned short* ap = cur + arow2 * KSS + hl * 8;
#pragma unroll
    for (int ks = 0; ks < 9; ++ks) {
      const short8 a = *(const short8*)(ap + ks * 16);
      const short8 bc = breg[ks];
      if (k < NCH2 - 1)
        breg[ks] = *(const short8*)(wb2 + (k + 1) * KC + ks * 16);
      acc2 = __builtin_amdgcn_mfma_f32_32x32x16_bf16(a, bc, acc2, 0, 0, 0);
    }
    __syncthreads();
  }

  // ==================== Epilogue: residual + store ====================
  const int c = ng2 * 32 + ln31;
#pragma unroll
  for (int g = 0; g < 4; ++g) {
    const int tbase = t0 + mg2 * 32 + 4 * hl + 8 * g;
    const size_t base = ((size_t)b * Cn + c) * Tn + tbase;
    const float4 uin = *(const float4*)(U + base);
    float4 o;
    o.x = uin.x + acc2[g * 4 + 0];
    o.y = uin.y + acc2[g * 4 + 1];
    o.z = uin.z + acc2[g * 4 + 2];
    o.w = uin.w + acc2[g * 4 + 3];
    *(float4*)(out + base) = o;
  }
}

extern "C" void kernel_launch(void* const* d_in, const int* in_sizes, int n_in,
                              void* d_out, int out_size, void* d_ws,
                              size_t ws_size, hipStream_t stream) {
  const float* U = (const float*)d_in[0];
  const float* ln_w = (const float*)d_in[1];
  const float* ln_b = (const float*)d_in[2];
  const float* bw1 = (const float*)d_in[3];
  const float* sw1 = (const float*)d_in[4];
  const float* ss1 = (const float*)d_in[5];
  const float* bw2 = (const float*)d_in[6];
  const float* sw2 = (const float*)d_in[7];
  const float* ss2 = (const float*)d_in[8];
  float* out = (float*)d_out;

  float* stats = (float*)d_ws;  // 64*8 floats
  unsigned short* W1p = (unsigned short*)((char*)d_ws + 4096);
  unsigned short* W2p = W1p + (size_t)Hn * K1;

  kan_prep<<<512, 256, 0, stream>>>(U, bw1, sw1, ss1, bw2, sw2, ss2, W1p, W2p,
                                    stats);
  kan_fused<<<Bn * TB, 512, 0, stream>>>(U, ln_w, ln_b, W1p, W2p, stats, out);
}